// Round 6
// baseline (407.618 us; speedup 1.0000x reference)
//
#include <hip/hip_runtime.h>
#include <math.h>
#include <type_traits>

typedef __bf16 bf16;
typedef __attribute__((ext_vector_type(8))) __bf16 bf16x8;
typedef __attribute__((ext_vector_type(4))) float f32x4;
typedef __attribute__((ext_vector_type(16))) float f32x16;

#define SEQ 2048
#define DM 1024
#define NH 16
#define HD 64
#define BATCH 4

#define NEG_BIG (-1e30f)
// softmax in exp2 domain: p = 2^(s * (1/8) * log2(e))
#define SCALE_L2E 0.18033688011f

__device__ inline bf16x8 cvt_f32x8(const float* p) {
  f32x4 x0 = *(const f32x4*)p;
  f32x4 x1 = *(const f32x4*)(p + 4);
  bf16x8 r;
  r[0] = (bf16)x0[0]; r[1] = (bf16)x0[1]; r[2] = (bf16)x0[2]; r[3] = (bf16)x0[3];
  r[4] = (bf16)x1[0]; r[5] = (bf16)x1[1]; r[6] = (bf16)x1[2]; r[7] = (bf16)x1[3];
  return r;
}

// async global->LDS DMA, 16 B per lane; LDS dest is wave-uniform base, HW
// writes lane i at base + i*16 (m97 pattern).
__device__ inline void async_copy16(const bf16* g, bf16* l) {
  __builtin_amdgcn_global_load_lds(
      (const __attribute__((address_space(1))) unsigned int*)g,
      (__attribute__((address_space(3))) unsigned int*)l, 16, 0, 0);
}

// ---------------------------------------------------------------------------
// f32 -> bf16 elementwise convert (memory-bound pre-pass), 8 elems/thread.
// ---------------------------------------------------------------------------
__global__ __launch_bounds__(256) void cvt_kernel(const float* __restrict__ src,
                                                  bf16* __restrict__ dst) {
  size_t i = ((size_t)blockIdx.x * 256 + threadIdx.x) * 8;
  *(bf16x8*)(dst + i) = cvt_f32x8(src + i);
}

// ---------------------------------------------------------------------------
// Weight transpose + f32->bf16 convert: Wt[n][k] = (bf16)W[k][n], 1024x1024.
// ---------------------------------------------------------------------------
__global__ __launch_bounds__(256) void transpose_w_kernel(
    const float* __restrict__ Wq, const float* __restrict__ Wk,
    const float* __restrict__ Wv, const float* __restrict__ Wo,
    bf16* __restrict__ Tq, bf16* __restrict__ Tk,
    bf16* __restrict__ Tv, bf16* __restrict__ To) {
  __shared__ bf16 tile[64 * 66];
  int z = blockIdx.z;
  const float* src = (z == 0) ? Wq : (z == 1) ? Wk : (z == 2) ? Wv : Wo;
  bf16* dst = (z == 0) ? Tq : (z == 1) ? Tk : (z == 2) ? Tv : To;
  int n0 = blockIdx.x * 64, k0 = blockIdx.y * 64;
  int t = threadIdx.x;
  int c = t & 63, rr = t >> 6;
#pragma unroll
  for (int i = 0; i < 16; i++) {
    int k = i * 4 + rr;
    tile[k * 66 + c] = (bf16)src[(size_t)(k0 + k) * DM + n0 + c];
  }
  __syncthreads();
#pragma unroll
  for (int i = 0; i < 16; i++) {
    int n = i * 4 + rr;
    dst[(size_t)(n0 + n) * DM + k0 + c] = tile[c * 66 + n];
  }
}

// ---------------------------------------------------------------------------
// V transpose from COMPACT per-head layout:
//   Vc[((b*16+h)*2048 + s)*64 + d]  ->  Vt[((b*16+h)*64 + d)*2048 + s]
// ---------------------------------------------------------------------------
__global__ __launch_bounds__(256) void transpose_v_kernel(
    const bf16* __restrict__ Vc, bf16* __restrict__ Vt) {
  __shared__ bf16 tile[64 * 66];
  int s0 = blockIdx.x * 64;
  int bh = blockIdx.y;  // b*16+h
  int t = threadIdx.x;
  int c = t & 63, rr = t >> 6;
  const bf16* src = Vc + (size_t)bh * SEQ * HD;
  bf16* dst = Vt + (size_t)bh * HD * SEQ;
#pragma unroll
  for (int i = 0; i < 16; i++) {
    int s = i * 4 + rr;
    tile[s * 66 + c] = src[(size_t)(s0 + s) * HD + c];
  }
  __syncthreads();
#pragma unroll
  for (int i = 0; i < 16; i++) {
    int d = i * 4 + rr;
    dst[(size_t)d * SEQ + s0 + c] = tile[c * 66 + d];
  }
}

// ---------------------------------------------------------------------------
// GEMM + bias (round-5 version — measured faster than the k-outer/BK=64
// variant). MODE 0: C[row*1024+col] (type CT).  MODE 1: compact per-head bf16
// C[((b*16+h)*2048+s)*64+d] with b=row>>11, s=row&2047, h=col>>6, d=col&63.
// ---------------------------------------------------------------------------
template <typename CT, int MODE>
__global__ __launch_bounds__(256) void gemm_bias_kernel(
    const bf16* __restrict__ A, const bf16* __restrict__ Bt,
    const float* __restrict__ bias, CT* __restrict__ C) {
  __shared__ bf16 As[128 * 32];
  __shared__ bf16 Bs[128 * 32];
  int m0 = blockIdx.x * 128, n0 = blockIdx.y * 128;
  int t = threadIdx.x;
  int wave = t >> 6, lane = t & 63, lr = lane & 15, lq = lane >> 4;
  int wm = (wave & 1) * 64, wn = (wave >> 1) * 64;

  f32x4 acc[4][4];
#pragma unroll
  for (int i = 0; i < 4; i++)
#pragma unroll
    for (int j = 0; j < 4; j++) acc[i][j] = (f32x4){0.f, 0.f, 0.f, 0.f};

  int srow = wave * 32 + (lane >> 2);
  int skc = lane & 3;
  const bf16* gA0 = A + (size_t)(m0 + srow) * DM + skc * 8;
  const bf16* gA1 = gA0 + (size_t)16 * DM;
  const bf16* gB0 = Bt + (size_t)(n0 + srow) * DM + skc * 8;
  const bf16* gB1 = gB0 + (size_t)16 * DM;
  bf16* lA0 = &As[(wave * 128) * 8];
  bf16* lA1 = &As[(wave * 128 + 64) * 8];
  bf16* lB0 = &Bs[(wave * 128) * 8];
  bf16* lB1 = &Bs[(wave * 128 + 64) * 8];

  for (int k0 = 0; k0 < DM; k0 += 32) {
    async_copy16(gA0, lA0);
    async_copy16(gA1, lA1);
    async_copy16(gB0, lB0);
    async_copy16(gB1, lB1);
    gA0 += 32; gA1 += 32; gB0 += 32; gB1 += 32;
    __syncthreads();

    bf16x8 af[4], bfr[4];
#pragma unroll
    for (int i = 0; i < 4; i++)
      af[i] = *(const bf16x8*)&As[(wm + i * 16 + lr) * 32 + lq * 8];
#pragma unroll
    for (int j = 0; j < 4; j++)
      bfr[j] = *(const bf16x8*)&Bs[(wn + j * 16 + lr) * 32 + lq * 8];
#pragma unroll
    for (int i = 0; i < 4; i++)
#pragma unroll
      for (int j = 0; j < 4; j++)
        acc[i][j] = __builtin_amdgcn_mfma_f32_16x16x32_bf16(af[i], bfr[j],
                                                            acc[i][j], 0, 0, 0);
    __syncthreads();
  }

  // Epilogue: C/D layout col = lane&15, row = (lane>>4)*4 + reg
#pragma unroll
  for (int j = 0; j < 4; j++) {
    int col = n0 + wn + j * 16 + lr;
    float bv = bias[col];
#pragma unroll
    for (int i = 0; i < 4; i++) {
      int row0 = m0 + wm + i * 16 + lq * 4;
#pragma unroll
      for (int r = 0; r < 4; r++) {
        int row = row0 + r;
        float v = acc[i][j][r] + bv;
        if constexpr (MODE == 0) {
          C[(size_t)row * DM + col] = (CT)v;
        } else {
          int b = row >> 11, s = row & 2047, h = col >> 6, d = col & 63;
          C[((size_t)(b * NH + h) * SEQ + s) * HD + d] = (CT)v;
        }
      }
    }
  }
}

// ---------------------------------------------------------------------------
// Flash attention v10 (causal): v9 minus the residency cap.
// v9 post-mortem: XCD swizzle verified (FETCH 148->42MB) but occupancy PINNED
// at 21% (2 waves/SIMD) despite 4x blocks; dur unchanged. Audit of the
// 64-key chunk's live state: qf16+o32+kf32+vf32+s32 ~= 154 regs > 128 ->
// per m69's 64/128/256 occupancy steps, allocation lands in the 2-waves/SIMD
// bucket (rocprof's VGPR=100 likely excludes AGPR-held accs). Fix:
//  1) REGISTER DIET: 32-key chunks -> kf 16, vf 16, s 16; peak ~= 112 regs.
//     MFMA/key unchanged (8 MFMA / 32 keys). nch = tq+1 chunks, kv-split
//     halves preserved.
//  2) occupancy attrs: plain __launch_bounds__(256) (the ",2" form may cap
//     waves/EU on this toolchain) + amdgpu_waves_per_eu(4,8): allocator must
//     fit 4 waves/EU (<=128 total, natural ~112 -> no spill), residency may
//     reach 8.
// Kept: XCD swizzle, kv-split + LDS merge, s_setprio around MFMA.
// ---------------------------------------------------------------------------
__attribute__((amdgpu_waves_per_eu(4, 8)))
__global__ __launch_bounds__(256) void attention_kernel(
    const bf16* __restrict__ Qc, const bf16* __restrict__ Kc,
    const bf16* __restrict__ Vt, bf16* __restrict__ ctx) {
  __shared__ float ls_o[2][2][16][64];  // [pair][dt][r][lane], sub1's O
  __shared__ float ls_ml[2][2][64];     // [pair][{m,l}][lane]

  int t = threadIdx.x, wave = t >> 6, lane = t & 63;
  int l31 = lane & 31, hh = lane >> 5;
  int pair = wave >> 1, sub = wave & 1;

  // XCD swizzle decode (bijective): xcd = bid&7 owns (b,h) groups with
  // g&7 == xcd; 32 blocks per group, 8 groups per XCD.
  int bid = blockIdx.x;
  int xcd = bid & 7, qq = bid >> 3;   // qq in 0..255
  int g = xcd + 8 * (qq & 7);         // (b,h) group 0..63
  int bx = qq >> 3;                   // 0..31
  int h = g & 15, b = g >> 4;

  int tq = pair ? (63 - bx) : bx;
  int q0 = tq * 32;
  int nch = tq + 1;                   // 32-key chunks for this tile
  int half = nch >> 1;
  int c0 = sub ? half : 0;            // this wave's chunk range [c0, c1)
  int c1 = sub ? nch : half;

  const bf16* Qb = Qc + (size_t)(b * NH + h) * SEQ * HD;
  const bf16* Kb = Kc + (size_t)(b * NH + h) * SEQ * HD;
  const bf16* Vb = Vt + (size_t)(b * NH + h) * HD * SEQ;
  bf16* Cb = ctx + (size_t)b * SEQ * DM + h * HD;

  // Q fragments: B-operand, col=query=l31, k(d) = st*16 + hh*8 + j
  bf16x8 qf[4];
#pragma unroll
  for (int st = 0; st < 4; st++)
    qf[st] = *(const bf16x8*)&Qb[(size_t)(q0 + l31) * HD + st * 16 + hh * 8];

  f32x16 o[2];
#pragma unroll
  for (int dt = 0; dt < 2; dt++)
#pragma unroll
    for (int r = 0; r < 16; r++) o[dt][r] = 0.f;
  float m_st = NEG_BIG, l_st = 0.f;

#pragma unroll 1
  for (int c = c0; c < c1; c++) {
    int kv0 = c * 32;
    // K frags: A-operand, row=key=kv0+l31, k(d) = st*16 + hh*8 + j
    bf16x8 kf[4];
#pragma unroll
    for (int st = 0; st < 4; st++)
      kf[st] = *(const bf16x8*)&Kb[(size_t)(kv0 + l31) * HD + st * 16 + hh * 8];
    // V^T frags: A-operand, row=d=dt*32+l31, k(key) = ks*16 + hh*8 + j
    bf16x8 vf[2][2];
#pragma unroll
    for (int dt = 0; dt < 2; dt++)
#pragma unroll
      for (int ks = 0; ks < 2; ks++)
        vf[dt][ks] = *(const bf16x8*)&Vb[(size_t)(dt * 32 + l31) * SEQ + kv0 +
                                         ks * 16 + hh * 8];

    // QK^T: s = D[key][query]; lane: query=l31,
    // key = kv0 + (r&3) + 8*(r>>2) + 4*hh
    f32x16 s;
#pragma unroll
    for (int r = 0; r < 16; r++) s[r] = 0.f;
    __builtin_amdgcn_s_setprio(1);
#pragma unroll
    for (int st = 0; st < 4; st++)
      s = __builtin_amdgcn_mfma_f32_32x32x16_bf16(kf[st], qf[st], s, 0, 0, 0);
    __builtin_amdgcn_s_setprio(0);

    bool diag = (c == nch - 1);  // only ever true for sub==1 (or nch==1)
    if (diag) {
      int q_g = q0 + l31;
#pragma unroll
      for (int r = 0; r < 16; r++) {
        int key = kv0 + (r & 3) + 8 * (r >> 2) + 4 * hh;
        float v = s[r] * SCALE_L2E;
        s[r] = (key > q_g) ? NEG_BIG : v;
      }
    } else {
#pragma unroll
      for (int r = 0; r < 16; r++) s[r] *= SCALE_L2E;
    }

    // online softmax: lane-local scalars, one cross-half merge each
    float mx = s[0];
#pragma unroll
    for (int r = 1; r < 16; r++) mx = fmaxf(mx, s[r]);
    mx = fmaxf(mx, __shfl_xor(mx, 32));
    float mnew = fmaxf(m_st, mx);
    float alpha = exp2f(m_st - mnew);
    m_st = mnew;
    float rs = 0.f;
#pragma unroll
    for (int r = 0; r < 16; r++) {
      float pv = exp2f(s[r] - mnew);
      s[r] = pv;
      rs += pv;
    }
    rs += __shfl_xor(rs, 32);
    l_st = l_st * alpha + rs;
#pragma unroll
    for (int dt = 0; dt < 2; dt++)
#pragma unroll
      for (int r = 0; r < 16; r++) o[dt][r] *= alpha;

    // pack P (adjacent-key pairs) then half-swap to build PV B-frags.
    unsigned int W[8];
#pragma unroll
    for (int w = 0; w < 8; w++) {
      unsigned int u;
      asm("v_cvt_pk_bf16_f32 %0, %1, %2"
          : "=v"(u)
          : "v"(s[2 * w]), "v"(s[2 * w + 1]));
      W[w] = u;
    }
    // B-frag for k-slot ks: lane holds keys 16*ks + 8*hh + {0..7}.
    // h=0 lanes need partner's W0,W1,W4,W5; h=1 need partner's W2,W3,W6,W7.
    bf16x8 pf[2];
    {
      unsigned int x1 = hh ? W[0] : W[2];
      unsigned int x2 = hh ? W[1] : W[3];
      unsigned int x3 = hh ? W[4] : W[6];
      unsigned int x4 = hh ? W[5] : W[7];
      unsigned int y1 = (unsigned int)__shfl_xor((int)x1, 32);
      unsigned int y2 = (unsigned int)__shfl_xor((int)x2, 32);
      unsigned int y3 = (unsigned int)__shfl_xor((int)x3, 32);
      unsigned int y4 = (unsigned int)__shfl_xor((int)x4, 32);
      unsigned int* f0 = (unsigned int*)&pf[0];
      unsigned int* f1 = (unsigned int*)&pf[1];
      f0[0] = hh ? y1 : W[0];
      f0[1] = hh ? y2 : W[1];
      f0[2] = hh ? W[2] : y1;
      f0[3] = hh ? W[3] : y2;
      f1[0] = hh ? y3 : W[4];
      f1[1] = hh ? y4 : W[5];
      f1[2] = hh ? W[6] : y3;
      f1[3] = hh ? W[7] : y4;
    }

    // PV: O^T[d][query] += V^T x P ; A=vf (row=d), B=pf (col=query)
    __builtin_amdgcn_s_setprio(1);
#pragma unroll
    for (int dt = 0; dt < 2; dt++)
#pragma unroll
      for (int ks = 0; ks < 2; ks++)
        o[dt] = __builtin_amdgcn_mfma_f32_32x32x16_bf16(vf[dt][ks], pf[ks],
                                                        o[dt], 0, 0, 0);
    __builtin_amdgcn_s_setprio(0);
  }

  // cross-wave merge of the two kv halves (sub1 -> LDS, sub0 merges+stores)
  if (sub) {
#pragma unroll
    for (int dt = 0; dt < 2; dt++)
#pragma unroll
      for (int r = 0; r < 16; r++) ls_o[pair][dt][r][lane] = o[dt][r];
    ls_ml[pair][0][lane] = m_st;
    ls_ml[pair][1][lane] = l_st;
  }
  __syncthreads();
  if (!sub) {
    float m2 = ls_ml[pair][0][lane], l2 = ls_ml[pair][1][lane];
    float m = fmaxf(m_st, m2);
    float a1 = exp2f(m_st - m), a2 = exp2f(m2 - m);
    float linv = 1.f / (l_st * a1 + l2 * a2);
    int row = q0 + l31;
#pragma unroll
    for (int dt = 0; dt < 2; dt++)
#pragma unroll
      for (int r = 0; r < 16; r += 2) {
        float va = (o[dt][r] * a1 + ls_o[pair][dt][r][lane] * a2) * linv;
        float vb =
            (o[dt][r + 1] * a1 + ls_o[pair][dt][r + 1][lane] * a2) * linv;
        unsigned int u;
        asm("v_cvt_pk_bf16_f32 %0, %1, %2" : "=v"(u) : "v"(va), "v"(vb));
        int d = dt * 32 + (r & 3) + 8 * (r >> 2) + 4 * hh;
        *(unsigned int*)&Cb[(size_t)row * DM + d] = u;
      }
  }
}

// ---------------------------------------------------------------------------
// I/O: ALL inputs float32, output float32 (32 MB). Internals bf16.
// ws (56 MB):  [0,8)MB 4x Wt bf16 | [8,24) Qc compact | [24,40) Kc compact |
// [40,56) Vc compact, later ctx.  d_out reuse: X (bf16 cvt buffer), then V^T
// scratch, then final f32 C. Sequential on one stream -> no liveness overlap.
// ---------------------------------------------------------------------------
extern "C" void kernel_launch(void* const* d_in, const int* in_sizes, int n_in,
                              void* d_out, int out_size, void* d_ws,
                              size_t ws_size, hipStream_t stream) {
  const float* iq = (const float*)d_in[0];
  const float* ik = (const float*)d_in[1];
  const float* iv = (const float*)d_in[2];
  const float* Wq = (const float*)d_in[3];
  const float* bq = (const float*)d_in[4];
  const float* Wk = (const float*)d_in[5];
  const float* bk = (const float*)d_in[6];
  const float* Wv = (const float*)d_in[7];
  const float* bv = (const float*)d_in[8];
  const float* Wo = (const float*)d_in[9];
  const float* bo = (const float*)d_in[10];

  char* ws = (char*)d_ws;
  const size_t MB = 1024 * 1024;
  bf16* Tq = (bf16*)(ws + 0 * MB);
  bf16* Tk = (bf16*)(ws + 2 * MB);
  bf16* Tv = (bf16*)(ws + 4 * MB);
  bf16* To = (bf16*)(ws + 6 * MB);
  bf16* Qc = (bf16*)(ws + 8 * MB);   // compact [B,H,S,64]
  bf16* Kc = (bf16*)(ws + 24 * MB);  // compact [B,H,S,64]
  bf16* Vc = (bf16*)(ws + 40 * MB);  // compact [B,H,S,64]
  bf16* X = (bf16*)d_out;    // bf16 input-cvt buffer / later V^T scratch
  bf16* Vtp = (bf16*)d_out;  // same region, sequential reuse
  bf16* Cx = Vc;             // ctx aliases Vc (dead after transpose_v)

  transpose_w_kernel<<<dim3(16, 16, 4), 256, 0, stream>>>(Wq, Wk, Wv, Wo, Tq,
                                                          Tk, Tv, To);
  cvt_kernel<<<dim3(4096), 256, 0, stream>>>(iq, X);
  gemm_bias_kernel<bf16, 1><<<dim3(64, 8), 256, 0, stream>>>(X, Tq, bq, Qc);
  cvt_kernel<<<dim3(4096), 256, 0, stream>>>(ik, X);
  gemm_bias_kernel<bf16, 1><<<dim3(64, 8), 256, 0, stream>>>(X, Tk, bk, Kc);
  cvt_kernel<<<dim3(4096), 256, 0, stream>>>(iv, X);
  gemm_bias_kernel<bf16, 1><<<dim3(64, 8), 256, 0, stream>>>(X, Tv, bv, Vc);
  transpose_v_kernel<<<dim3(32, 64), 256, 0, stream>>>(Vc, Vtp);
  attention_kernel<<<dim3(2048), 256, 0, stream>>>(Qc, Kc, Vtp, Cx);
  gemm_bias_kernel<float, 0><<<dim3(64, 8), 256, 0, stream>>>(Cx, To, bo,
                                                              (float*)d_out);
}

// Round 7
// 403.351 us; speedup vs baseline: 1.0106x; 1.0106x over previous
//
#include <hip/hip_runtime.h>
#include <math.h>
#include <type_traits>

typedef __bf16 bf16;
typedef __attribute__((ext_vector_type(8))) __bf16 bf16x8;
typedef __attribute__((ext_vector_type(4))) float f32x4;
typedef __attribute__((ext_vector_type(16))) float f32x16;

#define SEQ 2048
#define DM 1024
#define NH 16
#define HD 64
#define BATCH 4

#define NEG_BIG (-1e30f)
// softmax in exp2 domain: p = 2^(s * (1/8) * log2(e))
#define SCALE_L2E 0.18033688011f

__device__ inline bf16x8 cvt_f32x8(const float* p) {
  f32x4 x0 = *(const f32x4*)p;
  f32x4 x1 = *(const f32x4*)(p + 4);
  bf16x8 r;
  r[0] = (bf16)x0[0]; r[1] = (bf16)x0[1]; r[2] = (bf16)x0[2]; r[3] = (bf16)x0[3];
  r[4] = (bf16)x1[0]; r[5] = (bf16)x1[1]; r[6] = (bf16)x1[2]; r[7] = (bf16)x1[3];
  return r;
}

// async global->LDS DMA, 16 B per lane; LDS dest is wave-uniform base, HW
// writes lane i at base + i*16 (m97 pattern).
__device__ inline void async_copy16(const bf16* g, bf16* l) {
  __builtin_amdgcn_global_load_lds(
      (const __attribute__((address_space(1))) unsigned int*)g,
      (__attribute__((address_space(3))) unsigned int*)l, 16, 0, 0);
}

// ---------------------------------------------------------------------------
// f32 -> bf16 elementwise convert (memory-bound pre-pass), 8 elems/thread.
// ---------------------------------------------------------------------------
__global__ __launch_bounds__(256) void cvt_kernel(const float* __restrict__ src,
                                                  bf16* __restrict__ dst) {
  size_t i = ((size_t)blockIdx.x * 256 + threadIdx.x) * 8;
  *(bf16x8*)(dst + i) = cvt_f32x8(src + i);
}

// ---------------------------------------------------------------------------
// Weight transpose + f32->bf16 convert: Wt[n][k] = (bf16)W[k][n], 1024x1024.
// ---------------------------------------------------------------------------
__global__ __launch_bounds__(256) void transpose_w_kernel(
    const float* __restrict__ Wq, const float* __restrict__ Wk,
    const float* __restrict__ Wv, const float* __restrict__ Wo,
    bf16* __restrict__ Tq, bf16* __restrict__ Tk,
    bf16* __restrict__ Tv, bf16* __restrict__ To) {
  __shared__ bf16 tile[64 * 66];
  int z = blockIdx.z;
  const float* src = (z == 0) ? Wq : (z == 1) ? Wk : (z == 2) ? Wv : Wo;
  bf16* dst = (z == 0) ? Tq : (z == 1) ? Tk : (z == 2) ? Tv : To;
  int n0 = blockIdx.x * 64, k0 = blockIdx.y * 64;
  int t = threadIdx.x;
  int c = t & 63, rr = t >> 6;
#pragma unroll
  for (int i = 0; i < 16; i++) {
    int k = i * 4 + rr;
    tile[k * 66 + c] = (bf16)src[(size_t)(k0 + k) * DM + n0 + c];
  }
  __syncthreads();
#pragma unroll
  for (int i = 0; i < 16; i++) {
    int n = i * 4 + rr;
    dst[(size_t)(n0 + n) * DM + k0 + c] = tile[c * 66 + n];
  }
}

// ---------------------------------------------------------------------------
// GEMM + bias. MODE 0: C[row*1024+col] (type CT).  MODE 1: compact per-head
// bf16 C[((b*16+h)*2048+s)*64+d].  MODE 2: V^T direct — bf16
// C[((b*16+h)*64+d)*2048+s] (replaces the separate transpose_v kernel; the
// epilogue was already 2B scalar writes, so the scatter pattern cost is
// unchanged while 32MB of transpose traffic + one launch disappear).
// row = b*2048+s over 8192; col = h*64+d over 1024.
// ---------------------------------------------------------------------------
template <typename CT, int MODE>
__global__ __launch_bounds__(256) void gemm_bias_kernel(
    const bf16* __restrict__ A, const bf16* __restrict__ Bt,
    const float* __restrict__ bias, CT* __restrict__ C) {
  __shared__ bf16 As[128 * 32];
  __shared__ bf16 Bs[128 * 32];
  int m0 = blockIdx.x * 128, n0 = blockIdx.y * 128;
  int t = threadIdx.x;
  int wave = t >> 6, lane = t & 63, lr = lane & 15, lq = lane >> 4;
  int wm = (wave & 1) * 64, wn = (wave >> 1) * 64;

  f32x4 acc[4][4];
#pragma unroll
  for (int i = 0; i < 4; i++)
#pragma unroll
    for (int j = 0; j < 4; j++) acc[i][j] = (f32x4){0.f, 0.f, 0.f, 0.f};

  int srow = wave * 32 + (lane >> 2);
  int skc = lane & 3;
  const bf16* gA0 = A + (size_t)(m0 + srow) * DM + skc * 8;
  const bf16* gA1 = gA0 + (size_t)16 * DM;
  const bf16* gB0 = Bt + (size_t)(n0 + srow) * DM + skc * 8;
  const bf16* gB1 = gB0 + (size_t)16 * DM;
  bf16* lA0 = &As[(wave * 128) * 8];
  bf16* lA1 = &As[(wave * 128 + 64) * 8];
  bf16* lB0 = &Bs[(wave * 128) * 8];
  bf16* lB1 = &Bs[(wave * 128 + 64) * 8];

  for (int k0 = 0; k0 < DM; k0 += 32) {
    async_copy16(gA0, lA0);
    async_copy16(gA1, lA1);
    async_copy16(gB0, lB0);
    async_copy16(gB1, lB1);
    gA0 += 32; gA1 += 32; gB0 += 32; gB1 += 32;
    __syncthreads();

    bf16x8 af[4], bfr[4];
#pragma unroll
    for (int i = 0; i < 4; i++)
      af[i] = *(const bf16x8*)&As[(wm + i * 16 + lr) * 32 + lq * 8];
#pragma unroll
    for (int j = 0; j < 4; j++)
      bfr[j] = *(const bf16x8*)&Bs[(wn + j * 16 + lr) * 32 + lq * 8];
#pragma unroll
    for (int i = 0; i < 4; i++)
#pragma unroll
      for (int j = 0; j < 4; j++)
        acc[i][j] = __builtin_amdgcn_mfma_f32_16x16x32_bf16(af[i], bfr[j],
                                                            acc[i][j], 0, 0, 0);
    __syncthreads();
  }

  // Epilogue: C/D layout col = lane&15, row = (lane>>4)*4 + reg
#pragma unroll
  for (int j = 0; j < 4; j++) {
    int col = n0 + wn + j * 16 + lr;
    float bv = bias[col];
#pragma unroll
    for (int i = 0; i < 4; i++) {
      int row0 = m0 + wm + i * 16 + lq * 4;
#pragma unroll
      for (int r = 0; r < 4; r++) {
        int row = row0 + r;
        float v = acc[i][j][r] + bv;
        if constexpr (MODE == 0) {
          C[(size_t)row * DM + col] = (CT)v;
        } else if constexpr (MODE == 1) {
          int b = row >> 11, s = row & 2047, h = col >> 6, d = col & 63;
          C[((size_t)(b * NH + h) * SEQ + s) * HD + d] = (CT)v;
        } else {
          int b = row >> 11, s = row & 2047, h = col >> 6, d = col & 63;
          C[((size_t)(b * NH + h) * HD + d) * SEQ + s] = (CT)v;
        }
      }
    }
  }
}

// ---------------------------------------------------------------------------
// Flash attention v11 (causal): v10's verified 32x32 swapped compute body +
// REGISTER PING-PONG PREFETCH of K/V one 32-key chunk ahead.
// Post-mortems r4-r6: dur invariant ~140-145us while bank-conflicts 8.6M->0,
// FETCH 148->42MB, occupancy 12->40% (r6 via spill, WRITE +12MB). No shared
// pipe saturated (VALU 37%, MFMA 10%, HBM 7%) -> per-wave DEPENDENT-CHAIN
// latency with the K/V load wait inside it is the floor. v11 moves the loads
// off the chain: while chunk c computes, chunk c+1's kf/vf loads are in
// flight (issued ~full-chunk early instead of ~PV-issue early).
//  - 32-key chunks (kf 16 + vf 16 regs per buffer; x2 ping-pong = 64)
//  - odd chunk counts padded to even with a fully-masked chunk (mask math
//    makes it an exact no-op: all s -> NEG_BIG, exp2 -> 0, m/l unchanged)
//  - balanced (p, 63-p) two-pass pairing, 512 blocks x 4 waves
//  - no kv-split / no LDS merge (r5/r6: cost, no benefit), LDS = 0
//  - plain __launch_bounds__(256): natural VGPR alloc (waves_per_eu burned
//    us twice; spill tripwire = WRITE_SIZE > 20MB)
//  - XCD swizzle kept (proven FETCH 3.5x win)
// ---------------------------------------------------------------------------
__global__ __launch_bounds__(256) void attention_kernel(
    const bf16* __restrict__ Qc, const bf16* __restrict__ Kc,
    const bf16* __restrict__ Vt, bf16* __restrict__ ctx) {
  int t = threadIdx.x, wave = t >> 6, lane = t & 63;
  int l31 = lane & 31, hh = lane >> 5;

  // XCD swizzle decode (bijective over 512 blocks): all 8 blocks of one
  // (b,h) group land on one XCD (assuming bid%8 round-robin).
  int bid = blockIdx.x;
  int xcd = bid & 7, qq = bid >> 3;  // qq 0..63
  int g = xcd + 8 * (qq & 7);        // (b,h) group 0..63
  int bx = qq >> 3;                  // 0..7
  int h = g & 15, b = g >> 4;
  int p = bx * 4 + wave;             // pair index 0..31

  const bf16* Qb = Qc + (size_t)(b * NH + h) * SEQ * HD;
  const bf16* Kb = Kc + (size_t)(b * NH + h) * SEQ * HD;
  const bf16* Vb = Vt + (size_t)(b * NH + h) * HD * SEQ;
  bf16* Cb = ctx + (size_t)b * SEQ * DM + h * HD;

#pragma unroll 1
  for (int pass = 0; pass < 2; pass++) {
    int tq = pass ? (63 - p) : p;
    int q0 = tq * 32;
    int nch = tq + 1;              // true 32-key chunks
    int nch_ev = (nch + 1) & ~1;   // padded to even (pad chunk fully masked)

    // Q fragments: B-operand, col=query=l31, k(d) = st*16 + hh*8 + j
    bf16x8 qf[4];
#pragma unroll
    for (int st = 0; st < 4; st++)
      qf[st] = *(const bf16x8*)&Qb[(size_t)(q0 + l31) * HD + st * 16 + hh * 8];

    f32x16 o[2];
#pragma unroll
    for (int dt = 0; dt < 2; dt++)
#pragma unroll
      for (int r = 0; r < 16; r++) o[dt][r] = 0.f;
    float m_st = NEG_BIG, l_st = 0.f;

    bf16x8 kfA[4], vfA[2][2], kfB[4], vfB[2][2];

    auto loadkv = [&](bf16x8(&kf)[4], bf16x8(&vf)[2][2], int c) {
      int kv0 = c * 32;
#pragma unroll
      for (int st = 0; st < 4; st++)
        kf[st] =
            *(const bf16x8*)&Kb[(size_t)(kv0 + l31) * HD + st * 16 + hh * 8];
#pragma unroll
      for (int dt = 0; dt < 2; dt++)
#pragma unroll
        for (int ks = 0; ks < 2; ks++)
          vf[dt][ks] = *(const bf16x8*)&Vb[(size_t)(dt * 32 + l31) * SEQ + kv0 +
                                           ks * 16 + hh * 8];
    };

    auto compute = [&](bf16x8(&kf)[4], bf16x8(&vf)[2][2], int c) {
      int kv0 = c * 32;
      // QK^T: s = D[key][query]; query=l31, key = kv0+(r&3)+8*(r>>2)+4*hh
      f32x16 s;
#pragma unroll
      for (int r = 0; r < 16; r++) s[r] = 0.f;
      __builtin_amdgcn_s_setprio(1);
#pragma unroll
      for (int st = 0; st < 4; st++)
        s = __builtin_amdgcn_mfma_f32_32x32x16_bf16(kf[st], qf[st], s, 0, 0, 0);
      __builtin_amdgcn_s_setprio(0);

      if (c >= nch - 1) {  // diagonal chunk OR pad chunk (fully masked)
        int q_g = q0 + l31;
#pragma unroll
        for (int r = 0; r < 16; r++) {
          int key = kv0 + (r & 3) + 8 * (r >> 2) + 4 * hh;
          float v = s[r] * SCALE_L2E;
          s[r] = (key > q_g) ? NEG_BIG : v;
        }
      } else {
#pragma unroll
        for (int r = 0; r < 16; r++) s[r] *= SCALE_L2E;
      }

      // online softmax: lane-local scalars, one cross-half merge each
      float mx = s[0];
#pragma unroll
      for (int r = 1; r < 16; r++) mx = fmaxf(mx, s[r]);
      mx = fmaxf(mx, __shfl_xor(mx, 32));
      float mnew = fmaxf(m_st, mx);
      float alpha = exp2f(m_st - mnew);
      m_st = mnew;
      float rs = 0.f;
#pragma unroll
      for (int r = 0; r < 16; r++) {
        float pv = exp2f(s[r] - mnew);
        s[r] = pv;
        rs += pv;
      }
      rs += __shfl_xor(rs, 32);
      l_st = l_st * alpha + rs;
#pragma unroll
      for (int dt = 0; dt < 2; dt++)
#pragma unroll
        for (int r = 0; r < 16; r++) o[dt][r] *= alpha;

      // pack P (adjacent-key pairs) then half-swap to build PV B-frags.
      unsigned int W[8];
#pragma unroll
      for (int w = 0; w < 8; w++) {
        unsigned int u;
        asm("v_cvt_pk_bf16_f32 %0, %1, %2"
            : "=v"(u)
            : "v"(s[2 * w]), "v"(s[2 * w + 1]));
        W[w] = u;
      }
      bf16x8 pf[2];
      {
        unsigned int x1 = hh ? W[0] : W[2];
        unsigned int x2 = hh ? W[1] : W[3];
        unsigned int x3 = hh ? W[4] : W[6];
        unsigned int x4 = hh ? W[5] : W[7];
        unsigned int y1 = (unsigned int)__shfl_xor((int)x1, 32);
        unsigned int y2 = (unsigned int)__shfl_xor((int)x2, 32);
        unsigned int y3 = (unsigned int)__shfl_xor((int)x3, 32);
        unsigned int y4 = (unsigned int)__shfl_xor((int)x4, 32);
        unsigned int* f0 = (unsigned int*)&pf[0];
        unsigned int* f1 = (unsigned int*)&pf[1];
        f0[0] = hh ? y1 : W[0];
        f0[1] = hh ? y2 : W[1];
        f0[2] = hh ? W[2] : y1;
        f0[3] = hh ? W[3] : y2;
        f1[0] = hh ? y3 : W[4];
        f1[1] = hh ? y4 : W[5];
        f1[2] = hh ? W[6] : y3;
        f1[3] = hh ? W[7] : y4;
      }

      // PV: O^T[d][query] += V^T x P ; A=vf (row=d), B=pf (col=query)
      __builtin_amdgcn_s_setprio(1);
#pragma unroll
      for (int dt = 0; dt < 2; dt++)
#pragma unroll
        for (int ks = 0; ks < 2; ks++)
          o[dt] = __builtin_amdgcn_mfma_f32_32x32x16_bf16(vf[dt][ks], pf[ks],
                                                          o[dt], 0, 0, 0);
      __builtin_amdgcn_s_setprio(0);
    };

    // software pipeline: ping-pong A/B register buffers, one chunk ahead
    loadkv(kfA, vfA, 0);
#pragma unroll 1
    for (int c = 0; c < nch_ev; c += 2) {
      loadkv(kfB, vfB, c + 1);   // in flight while chunk c computes
      compute(kfA, vfA, c);
      if (c + 2 < nch_ev) loadkv(kfA, vfA, c + 2);  // in flight during c+1
      compute(kfB, vfB, c + 1);
    }

    // epilogue: query=l31 lane-local; d = dt*32 + (r&3)+8*(r>>2)+4*hh
    float inv = 1.f / l_st;
    int row = q0 + l31;
#pragma unroll
    for (int dt = 0; dt < 2; dt++)
#pragma unroll
      for (int r = 0; r < 16; r += 2) {
        float va = o[dt][r] * inv;
        float vb = o[dt][r + 1] * inv;
        unsigned int u;
        asm("v_cvt_pk_bf16_f32 %0, %1, %2" : "=v"(u) : "v"(va), "v"(vb));
        int d = dt * 32 + (r & 3) + 8 * (r >> 2) + 4 * hh;
        *(unsigned int*)&Cb[(size_t)row * DM + d] = u;
      }
  }
}

// ---------------------------------------------------------------------------
// I/O: ALL inputs float32, output float32 (32 MB). Internals bf16.
// ws (56 MB): [0,8) 4x Wt bf16 | [8,24) Qc | [24,40) Kc | [40,56) X (bf16
// cvt buffer), later ctx (X dead after V-GEMM reads it).
// d_out: V^T (written directly by MODE-2 V-GEMM), later final f32 C.
// Sequential on one stream -> no liveness overlap.
// ---------------------------------------------------------------------------
extern "C" void kernel_launch(void* const* d_in, const int* in_sizes, int n_in,
                              void* d_out, int out_size, void* d_ws,
                              size_t ws_size, hipStream_t stream) {
  const float* iq = (const float*)d_in[0];
  const float* ik = (const float*)d_in[1];
  const float* iv = (const float*)d_in[2];
  const float* Wq = (const float*)d_in[3];
  const float* bq = (const float*)d_in[4];
  const float* Wk = (const float*)d_in[5];
  const float* bk = (const float*)d_in[6];
  const float* Wv = (const float*)d_in[7];
  const float* bv = (const float*)d_in[8];
  const float* Wo = (const float*)d_in[9];
  const float* bo = (const float*)d_in[10];

  char* ws = (char*)d_ws;
  const size_t MB = 1024 * 1024;
  bf16* Tq = (bf16*)(ws + 0 * MB);
  bf16* Tk = (bf16*)(ws + 2 * MB);
  bf16* Tv = (bf16*)(ws + 4 * MB);
  bf16* To = (bf16*)(ws + 6 * MB);
  bf16* Qc = (bf16*)(ws + 8 * MB);   // compact [B,H,S,64]
  bf16* Kc = (bf16*)(ws + 24 * MB);  // compact [B,H,S,64]
  bf16* X = (bf16*)(ws + 40 * MB);   // bf16 input-cvt buffer
  bf16* Vtp = (bf16*)d_out;          // V^T [B,H,64,S], written by MODE-2 GEMM
  bf16* Cx = (bf16*)(ws + 40 * MB);  // ctx reuses X region (dead after V-GEMM)

  transpose_w_kernel<<<dim3(16, 16, 4), 256, 0, stream>>>(Wq, Wk, Wv, Wo, Tq,
                                                          Tk, Tv, To);
  cvt_kernel<<<dim3(4096), 256, 0, stream>>>(iq, X);
  gemm_bias_kernel<bf16, 1><<<dim3(64, 8), 256, 0, stream>>>(X, Tq, bq, Qc);
  cvt_kernel<<<dim3(4096), 256, 0, stream>>>(ik, X);
  gemm_bias_kernel<bf16, 1><<<dim3(64, 8), 256, 0, stream>>>(X, Tk, bk, Kc);
  cvt_kernel<<<dim3(4096), 256, 0, stream>>>(iv, X);
  gemm_bias_kernel<bf16, 2><<<dim3(64, 8), 256, 0, stream>>>(X, Tv, bv, Vtp);
  attention_kernel<<<dim3(512), 256, 0, stream>>>(Qc, Kc, Vtp, Cx);
  gemm_bias_kernel<float, 0><<<dim3(64, 8), 256, 0, stream>>>(Cx, To, bo,
                                                              (float*)d_out);
}

// Round 8
// 395.627 us; speedup vs baseline: 1.0303x; 1.0195x over previous
//
#include <hip/hip_runtime.h>
#include <math.h>
#include <type_traits>

typedef __bf16 bf16;
typedef __attribute__((ext_vector_type(8))) __bf16 bf16x8;
typedef __attribute__((ext_vector_type(4))) float f32x4;
typedef __attribute__((ext_vector_type(16))) float f32x16;

#define SEQ 2048
#define DM 1024
#define NH 16
#define HD 64
#define BATCH 4

#define NEG_BIG (-1e30f)
// softmax in exp2 domain: p = 2^(s * (1/8) * log2(e))
#define SCALE_L2E 0.18033688011f

__device__ inline bf16x8 cvt_f32x8(const float* p) {
  f32x4 x0 = *(const f32x4*)p;
  f32x4 x1 = *(const f32x4*)(p + 4);
  bf16x8 r;
  r[0] = (bf16)x0[0]; r[1] = (bf16)x0[1]; r[2] = (bf16)x0[2]; r[3] = (bf16)x0[3];
  r[4] = (bf16)x1[0]; r[5] = (bf16)x1[1]; r[6] = (bf16)x1[2]; r[7] = (bf16)x1[3];
  return r;
}

// async global->LDS DMA, 16 B per lane; LDS dest is wave-uniform base, HW
// writes lane i at base + i*16 (m97 pattern).
__device__ inline void async_copy16(const bf16* g, bf16* l) {
  __builtin_amdgcn_global_load_lds(
      (const __attribute__((address_space(1))) unsigned int*)g,
      (__attribute__((address_space(3))) unsigned int*)l, 16, 0, 0);
}

// ---------------------------------------------------------------------------
// f32 -> bf16 elementwise convert (memory-bound pre-pass), 8 elems/thread.
// ---------------------------------------------------------------------------
__global__ __launch_bounds__(256) void cvt_kernel(const float* __restrict__ src,
                                                  bf16* __restrict__ dst) {
  size_t i = ((size_t)blockIdx.x * 256 + threadIdx.x) * 8;
  *(bf16x8*)(dst + i) = cvt_f32x8(src + i);
}

// ---------------------------------------------------------------------------
// Weight transpose + f32->bf16 convert: Wt[n][k] = (bf16)W[k][n], 1024x1024.
// ---------------------------------------------------------------------------
__global__ __launch_bounds__(256) void transpose_w_kernel(
    const float* __restrict__ Wq, const float* __restrict__ Wk,
    const float* __restrict__ Wv, const float* __restrict__ Wo,
    bf16* __restrict__ Tq, bf16* __restrict__ Tk,
    bf16* __restrict__ Tv, bf16* __restrict__ To) {
  __shared__ bf16 tile[64 * 66];
  int z = blockIdx.z;
  const float* src = (z == 0) ? Wq : (z == 1) ? Wk : (z == 2) ? Wv : Wo;
  bf16* dst = (z == 0) ? Tq : (z == 1) ? Tk : (z == 2) ? Tv : To;
  int n0 = blockIdx.x * 64, k0 = blockIdx.y * 64;
  int t = threadIdx.x;
  int c = t & 63, rr = t >> 6;
#pragma unroll
  for (int i = 0; i < 16; i++) {
    int k = i * 4 + rr;
    tile[k * 66 + c] = (bf16)src[(size_t)(k0 + k) * DM + n0 + c];
  }
  __syncthreads();
#pragma unroll
  for (int i = 0; i < 16; i++) {
    int n = i * 4 + rr;
    dst[(size_t)(n0 + n) * DM + k0 + c] = tile[c * 66 + n];
  }
}

// ---------------------------------------------------------------------------
// GEMM + bias, v2: LDS DOUBLE-BUFFER 2-phase (T3-minimum).
// r7 post-mortem: pipeline ~220us sits in 4 GEMMs (~315 TF each). Old loop
// was stage -> barrier(vmcnt-drain) -> compute: ZERO load/compute overlap,
// and at 2 blocks/CU there's no TLP to cover the drain (m97's 874 TF relied
// on 3 blocks/CU; m102 shape curve: N=1024 -> 90 TF on that structure).
// New: stage(buf0); barrier; per K-step { stage(buf^1, k+32); compute(buf);
// barrier; } -> next tile's loads fly under the current tile's ds_read+MFMA,
// the barrier drains only the remainder (catalog 2-phase recipe).
// MODE 0: C[row*1024+col] (type CT).  MODE 1: compact per-head bf16.
// MODE 2: V^T direct (replaces transpose_v kernel).
// ---------------------------------------------------------------------------
template <typename CT, int MODE>
__global__ __launch_bounds__(256) void gemm_bias_kernel(
    const bf16* __restrict__ A, const bf16* __restrict__ Bt,
    const float* __restrict__ bias, CT* __restrict__ C) {
  __shared__ bf16 As[2][128 * 32];
  __shared__ bf16 Bs[2][128 * 32];
  int m0 = blockIdx.x * 128, n0 = blockIdx.y * 128;
  int t = threadIdx.x;
  int wave = t >> 6, lane = t & 63, lr = lane & 15, lq = lane >> 4;
  int wm = (wave & 1) * 64, wn = (wave >> 1) * 64;

  f32x4 acc[4][4];
#pragma unroll
  for (int i = 0; i < 4; i++)
#pragma unroll
    for (int j = 0; j < 4; j++) acc[i][j] = (f32x4){0.f, 0.f, 0.f, 0.f};

  // staging: wave w, chunk c: slot = w*128 + c*64 + lane; row = slot>>2,
  // kc = lane&3. 4 lanes cover 64 contiguous global bytes (16 segs/instr).
  int srow = wave * 32 + (lane >> 2);
  int skc = lane & 3;
  const bf16* gA0 = A + (size_t)(m0 + srow) * DM + skc * 8;
  const bf16* gA1 = gA0 + (size_t)16 * DM;
  const bf16* gB0 = Bt + (size_t)(n0 + srow) * DM + skc * 8;
  const bf16* gB1 = gB0 + (size_t)16 * DM;
  int oA0 = (wave * 128) * 8;
  int oA1 = (wave * 128 + 64) * 8;

  auto stage = [&](int buf) {
    async_copy16(gA0, &As[buf][oA0]);
    async_copy16(gA1, &As[buf][oA1]);
    async_copy16(gB0, &Bs[buf][oA0]);
    async_copy16(gB1, &Bs[buf][oA1]);
    gA0 += 32; gA1 += 32; gB0 += 32; gB1 += 32;
  };

  stage(0);
  __syncthreads();
  int cur = 0;
  for (int k0 = 0; k0 < DM; k0 += 32) {
    if (k0 + 32 < DM) stage(cur ^ 1);  // in flight under this tile's compute

    bf16x8 af[4], bfr[4];
#pragma unroll
    for (int i = 0; i < 4; i++)
      af[i] = *(const bf16x8*)&As[cur][(wm + i * 16 + lr) * 32 + lq * 8];
#pragma unroll
    for (int j = 0; j < 4; j++)
      bfr[j] = *(const bf16x8*)&Bs[cur][(wn + j * 16 + lr) * 32 + lq * 8];
    __builtin_amdgcn_s_setprio(1);
#pragma unroll
    for (int i = 0; i < 4; i++)
#pragma unroll
      for (int j = 0; j < 4; j++)
        acc[i][j] = __builtin_amdgcn_mfma_f32_16x16x32_bf16(af[i], bfr[j],
                                                            acc[i][j], 0, 0, 0);
    __builtin_amdgcn_s_setprio(0);
    __syncthreads();  // drains the in-flight stage (remainder only)
    cur ^= 1;
  }

  // Epilogue: C/D layout col = lane&15, row = (lane>>4)*4 + reg
#pragma unroll
  for (int j = 0; j < 4; j++) {
    int col = n0 + wn + j * 16 + lr;
    float bv = bias[col];
#pragma unroll
    for (int i = 0; i < 4; i++) {
      int row0 = m0 + wm + i * 16 + lq * 4;
#pragma unroll
      for (int r = 0; r < 4; r++) {
        int row = row0 + r;
        float v = acc[i][j][r] + bv;
        if constexpr (MODE == 0) {
          C[(size_t)row * DM + col] = (CT)v;
        } else if constexpr (MODE == 1) {
          int b = row >> 11, s = row & 2047, h = col >> 6, d = col & 63;
          C[((size_t)(b * NH + h) * SEQ + s) * HD + d] = (CT)v;
        } else {
          int b = row >> 11, s = row & 2047, h = col >> 6, d = col & 63;
          C[((size_t)(b * NH + h) * HD + d) * SEQ + s] = (CT)v;
        }
      }
    }
  }
}

// ---------------------------------------------------------------------------
// Flash attention v12 (causal): REVERT to the v8 64-key body (best measured,
// 140us) + XCD swizzle (independently proven: FETCH 148->~45MB, neutral
// time). r7 falsifier fired: ping-pong prefetch clean (VGPR 148, no spill)
// but 148us > v8's 140 -> per-wave load-latency is NOT the binding resource;
// attention is at its structural floor for this design. Dropped: kv-split
// (r5: cost), 32-key diet (r6: spill trade), ping-pong (r7: neutral-).
// Balanced (p, 63-p) two-pass pairing, 512 blocks x 4 waves.
// ---------------------------------------------------------------------------
__global__ __launch_bounds__(256, 2) void attention_kernel(
    const bf16* __restrict__ Qc, const bf16* __restrict__ Kc,
    const bf16* __restrict__ Vt, bf16* __restrict__ ctx) {
  int t = threadIdx.x, wave = t >> 6, lane = t & 63;
  int l31 = lane & 31, hh = lane >> 5;

  // XCD swizzle decode (bijective over 512 blocks): all 8 blocks of one
  // (b,h) group land on one XCD (assuming bid%8 round-robin).
  int bid = blockIdx.x;
  int xcd = bid & 7, qq = bid >> 3;  // qq 0..63
  int g = xcd + 8 * (qq & 7);        // (b,h) group 0..63
  int bx = qq >> 3;                  // 0..7
  int h = g & 15, b = g >> 4;
  int p = bx * 4 + wave;             // pair index 0..31

  const bf16* Qb = Qc + (size_t)(b * NH + h) * SEQ * HD;
  const bf16* Kb = Kc + (size_t)(b * NH + h) * SEQ * HD;
  const bf16* Vb = Vt + (size_t)(b * NH + h) * HD * SEQ;
  bf16* Cb = ctx + (size_t)b * SEQ * DM + h * HD;

#pragma unroll 1
  for (int pass = 0; pass < 2; pass++) {
    int tq = pass ? (63 - p) : p;
    int q0 = tq * 32;

    // Q fragments: B-operand, col=query=l31, k(d) = st*16 + hh*8 + j
    bf16x8 qf[4];
#pragma unroll
    for (int st = 0; st < 4; st++)
      qf[st] = *(const bf16x8*)&Qb[(size_t)(q0 + l31) * HD + st * 16 + hh * 8];

    f32x16 o[2];
#pragma unroll
    for (int dt = 0; dt < 2; dt++)
#pragma unroll
      for (int r = 0; r < 16; r++) o[dt][r] = 0.f;
    float m_st = NEG_BIG, l_st = 0.f;

    int nch = (tq >> 1) + 1;  // 64-key chunks; last one is diagonal
#pragma unroll 1
    for (int c = 0; c < nch; c++) {
      int kv0 = c * 64;
      // K frags: A-operand, row=key=kt*32+l31, k(d) = st*16 + hh*8 + j
      bf16x8 kf[2][4];
#pragma unroll
      for (int kt = 0; kt < 2; kt++)
#pragma unroll
        for (int st = 0; st < 4; st++)
          kf[kt][st] = *(const bf16x8*)&Kb[(size_t)(kv0 + kt * 32 + l31) * HD +
                                           st * 16 + hh * 8];
      // V^T frags: A-operand, row=d=dt*32+l31, k(key) = ks*16 + hh*8 + j
      bf16x8 vf[2][4];
#pragma unroll
      for (int dt = 0; dt < 2; dt++)
#pragma unroll
        for (int ks = 0; ks < 4; ks++)
          vf[dt][ks] = *(const bf16x8*)&Vb[(size_t)(dt * 32 + l31) * SEQ + kv0 +
                                           ks * 16 + hh * 8];

      // QK^T: s[kt] holds D[key][query]; lane: query=l31,
      // key = kv0 + kt*32 + (r&3) + 8*(r>>2) + 4*hh
      f32x16 s[2];
      __builtin_amdgcn_s_setprio(1);
#pragma unroll
      for (int kt = 0; kt < 2; kt++) {
        f32x16 acc;
#pragma unroll
        for (int r = 0; r < 16; r++) acc[r] = 0.f;
#pragma unroll
        for (int st = 0; st < 4; st++)
          acc = __builtin_amdgcn_mfma_f32_32x32x16_bf16(kf[kt][st], qf[st],
                                                        acc, 0, 0, 0);
        s[kt] = acc;
      }
      __builtin_amdgcn_s_setprio(0);

      bool diag = (c == nch - 1);
      if (diag) {
        int q_g = q0 + l31;
#pragma unroll
        for (int kt = 0; kt < 2; kt++)
#pragma unroll
          for (int r = 0; r < 16; r++) {
            int key = kv0 + kt * 32 + (r & 3) + 8 * (r >> 2) + 4 * hh;
            float v = s[kt][r] * SCALE_L2E;
            s[kt][r] = (key > q_g) ? NEG_BIG : v;
          }
      } else {
#pragma unroll
        for (int kt = 0; kt < 2; kt++)
#pragma unroll
          for (int r = 0; r < 16; r++) s[kt][r] *= SCALE_L2E;
      }

      // online softmax: lane-local scalars, one cross-half merge each
      float mx = s[0][0];
#pragma unroll
      for (int r = 1; r < 16; r++) mx = fmaxf(mx, s[0][r]);
#pragma unroll
      for (int r = 0; r < 16; r++) mx = fmaxf(mx, s[1][r]);
      mx = fmaxf(mx, __shfl_xor(mx, 32));
      float mnew = fmaxf(m_st, mx);
      float alpha = exp2f(m_st - mnew);
      m_st = mnew;
      float rs = 0.f;
#pragma unroll
      for (int kt = 0; kt < 2; kt++)
#pragma unroll
        for (int r = 0; r < 16; r++) {
          float pv = exp2f(s[kt][r] - mnew);
          s[kt][r] = pv;
          rs += pv;
        }
      rs += __shfl_xor(rs, 32);
      l_st = l_st * alpha + rs;
#pragma unroll
      for (int dt = 0; dt < 2; dt++)
#pragma unroll
        for (int r = 0; r < 16; r++) o[dt][r] *= alpha;

      // pack P (adjacent-key pairs) then half-swap to build PV B-frags.
      unsigned int W[2][8];
#pragma unroll
      for (int kt = 0; kt < 2; kt++)
#pragma unroll
        for (int w = 0; w < 8; w++) {
          unsigned int u;
          asm("v_cvt_pk_bf16_f32 %0, %1, %2"
              : "=v"(u)
              : "v"(s[kt][2 * w]), "v"(s[kt][2 * w + 1]));
          W[kt][w] = u;
        }
      // B-frag for k-slot ks: lane holds keys 16*ks + 8*hh + {0..7}.
      // h=0 lanes need partner's W0,W1,W4,W5; h=1 need partner's W2,W3,W6,W7.
      bf16x8 pf[4];
#pragma unroll
      for (int kt = 0; kt < 2; kt++) {
        unsigned int x1 = hh ? W[kt][0] : W[kt][2];
        unsigned int x2 = hh ? W[kt][1] : W[kt][3];
        unsigned int x3 = hh ? W[kt][4] : W[kt][6];
        unsigned int x4 = hh ? W[kt][5] : W[kt][7];
        unsigned int y1 = (unsigned int)__shfl_xor((int)x1, 32);
        unsigned int y2 = (unsigned int)__shfl_xor((int)x2, 32);
        unsigned int y3 = (unsigned int)__shfl_xor((int)x3, 32);
        unsigned int y4 = (unsigned int)__shfl_xor((int)x4, 32);
        unsigned int* f0 = (unsigned int*)&pf[2 * kt];
        unsigned int* f1 = (unsigned int*)&pf[2 * kt + 1];
        f0[0] = hh ? y1 : W[kt][0];
        f0[1] = hh ? y2 : W[kt][1];
        f0[2] = hh ? W[kt][2] : y1;
        f0[3] = hh ? W[kt][3] : y2;
        f1[0] = hh ? y3 : W[kt][4];
        f1[1] = hh ? y4 : W[kt][5];
        f1[2] = hh ? W[kt][6] : y3;
        f1[3] = hh ? W[kt][7] : y4;
      }

      // PV: O^T[d][query] += V^T x P ; A=vf (row=d), B=pf (col=query)
      __builtin_amdgcn_s_setprio(1);
#pragma unroll
      for (int dt = 0; dt < 2; dt++)
#pragma unroll
        for (int ks = 0; ks < 4; ks++)
          o[dt] = __builtin_amdgcn_mfma_f32_32x32x16_bf16(vf[dt][ks], pf[ks],
                                                          o[dt], 0, 0, 0);
      __builtin_amdgcn_s_setprio(0);
    }

    // epilogue: query=l31 lane-local; d = dt*32 + (r&3)+8*(r>>2)+4*hh
    float inv = 1.f / l_st;
    int row = q0 + l31;
#pragma unroll
    for (int dt = 0; dt < 2; dt++)
#pragma unroll
      for (int r = 0; r < 16; r += 2) {
        float va = o[dt][r] * inv;
        float vb = o[dt][r + 1] * inv;
        unsigned int u;
        asm("v_cvt_pk_bf16_f32 %0, %1, %2" : "=v"(u) : "v"(va), "v"(vb));
        int d = dt * 32 + (r & 3) + 8 * (r >> 2) + 4 * hh;
        *(unsigned int*)&Cb[(size_t)row * DM + d] = u;
      }
  }
}

// ---------------------------------------------------------------------------
// I/O: ALL inputs float32, output float32 (32 MB). Internals bf16.
// ws (56 MB): [0,8) 4x Wt bf16 | [8,24) Qc | [24,40) Kc | [40,56) X (bf16
// cvt buffer), later ctx (X dead after V-GEMM reads it).
// d_out: V^T (written directly by MODE-2 V-GEMM), later final f32 C.
// Sequential on one stream -> no liveness overlap.
// ---------------------------------------------------------------------------
extern "C" void kernel_launch(void* const* d_in, const int* in_sizes, int n_in,
                              void* d_out, int out_size, void* d_ws,
                              size_t ws_size, hipStream_t stream) {
  const float* iq = (const float*)d_in[0];
  const float* ik = (const float*)d_in[1];
  const float* iv = (const float*)d_in[2];
  const float* Wq = (const float*)d_in[3];
  const float* bq = (const float*)d_in[4];
  const float* Wk = (const float*)d_in[5];
  const float* bk = (const float*)d_in[6];
  const float* Wv = (const float*)d_in[7];
  const float* bv = (const float*)d_in[8];
  const float* Wo = (const float*)d_in[9];
  const float* bo = (const float*)d_in[10];

  char* ws = (char*)d_ws;
  const size_t MB = 1024 * 1024;
  bf16* Tq = (bf16*)(ws + 0 * MB);
  bf16* Tk = (bf16*)(ws + 2 * MB);
  bf16* Tv = (bf16*)(ws + 4 * MB);
  bf16* To = (bf16*)(ws + 6 * MB);
  bf16* Qc = (bf16*)(ws + 8 * MB);   // compact [B,H,S,64]
  bf16* Kc = (bf16*)(ws + 24 * MB);  // compact [B,H,S,64]
  bf16* X = (bf16*)(ws + 40 * MB);   // bf16 input-cvt buffer
  bf16* Vtp = (bf16*)d_out;          // V^T [B,H,64,S], written by MODE-2 GEMM
  bf16* Cx = (bf16*)(ws + 40 * MB);  // ctx reuses X region (dead after V-GEMM)

  transpose_w_kernel<<<dim3(16, 16, 4), 256, 0, stream>>>(Wq, Wk, Wv, Wo, Tq,
                                                          Tk, Tv, To);
  cvt_kernel<<<dim3(4096), 256, 0, stream>>>(iq, X);
  gemm_bias_kernel<bf16, 1><<<dim3(64, 8), 256, 0, stream>>>(X, Tq, bq, Qc);
  cvt_kernel<<<dim3(4096), 256, 0, stream>>>(ik, X);
  gemm_bias_kernel<bf16, 1><<<dim3(64, 8), 256, 0, stream>>>(X, Tk, bk, Kc);
  cvt_kernel<<<dim3(4096), 256, 0, stream>>>(iv, X);
  gemm_bias_kernel<bf16, 2><<<dim3(64, 8), 256, 0, stream>>>(X, Tv, bv, Vtp);
  attention_kernel<<<dim3(512), 256, 0, stream>>>(Qc, Kc, Vtp, Cx);
  gemm_bias_kernel<float, 0><<<dim3(64, 8), 256, 0, stream>>>(Cx, To, bo,
                                                              (float*)d_out);
}